// Round 1
// baseline (1025.110 us; speedup 1.0000x reference)
//
#include <hip/hip_runtime.h>

// Problem constants (from reference)
constexpr int F_IN    = 4;
constexpr int R       = 1024;
constexpr int C       = 4096;
constexpr int N_CELLS = 8192;

// One workgroup per (f, r) row pair. All gathers for a given (f,r) read the
// same 16 KiB input row; all scatters write out[f][r][.] and out[f+4][r][.].
// Stage the input row + both accumulator rows in LDS; scatter via LDS atomics.
__global__ __launch_bounds__(256) void scatter_mp3_kernel(
    const float* __restrict__ in,    // [F_IN][R][C]
    const int*   __restrict__ idx0,  // [N_CELLS]
    const int*   __restrict__ idx1,
    const int*   __restrict__ idx2,
    float*       __restrict__ out)   // [2*F_IN][R][C]
{
    __shared__ float row[C];   // 16 KiB: input row
    __shared__ float p0[C];    // 16 KiB: part0 accumulator
    __shared__ float p1[C];    // 16 KiB: part1 accumulator

    const int fr = blockIdx.x;             // 0 .. F_IN*R-1
    const float* __restrict__ src = in + (size_t)fr * C;

    // Load input row (vectorized) and zero accumulators.
    {
        const float4* src4 = reinterpret_cast<const float4*>(src);
        float4* row4 = reinterpret_cast<float4*>(row);
        float4* p04  = reinterpret_cast<float4*>(p0);
        float4* p14  = reinterpret_cast<float4*>(p1);
        const float4 z = make_float4(0.f, 0.f, 0.f, 0.f);
        for (int c = threadIdx.x; c < C / 4; c += blockDim.x) {
            row4[c] = src4[c];
            p04[c] = z;
            p14[c] = z;
        }
    }
    __syncthreads();

    // Each thread handles N_CELLS/blockDim cells with coalesced idx loads.
    for (int n = threadIdx.x; n < N_CELLS; n += blockDim.x) {
        const int i0 = idx0[n];
        const int i1 = idx1[n];
        const int i2 = idx2[n];
        const float a = row[i0];
        const float b = row[i1];
        const float c = row[i2];
        const float ab = a * b;
        const float bc = b * c;
        const float ac = a * c;
        const float abc = ab * c;
        atomicAdd(&p0[i0], abc);
        atomicAdd(&p0[i1], abc);
        atomicAdd(&p0[i2], abc);
        atomicAdd(&p1[i0], bc);
        atomicAdd(&p1[i1], ac);
        atomicAdd(&p1[i2], ab);
    }
    __syncthreads();

    // Coalesced store of both output rows.
    float* __restrict__ out0 = out + (size_t)fr * C;                       // part0: f in [0,4)
    float* __restrict__ out1 = out + (size_t)F_IN * R * C + (size_t)fr * C; // part1: f+4
    {
        const float4* p04 = reinterpret_cast<const float4*>(p0);
        const float4* p14 = reinterpret_cast<const float4*>(p1);
        float4* o0 = reinterpret_cast<float4*>(out0);
        float4* o1 = reinterpret_cast<float4*>(out1);
        for (int c = threadIdx.x; c < C / 4; c += blockDim.x) {
            o0[c] = p04[c];
            o1[c] = p14[c];
        }
    }
}

extern "C" void kernel_launch(void* const* d_in, const int* in_sizes, int n_in,
                              void* d_out, int out_size, void* d_ws, size_t ws_size,
                              hipStream_t stream) {
    const float* in   = (const float*)d_in[0];
    const int*   idx0 = (const int*)d_in[1];
    const int*   idx1 = (const int*)d_in[2];
    const int*   idx2 = (const int*)d_in[3];
    float* out = (float*)d_out;

    dim3 grid(F_IN * R);   // 4096 workgroups, one per (f, r)
    dim3 block(256);
    scatter_mp3_kernel<<<grid, block, 0, stream>>>(in, idx0, idx1, idx2, out);
}

// Round 2
// 133.923 us; speedup vs baseline: 7.6545x; 7.6545x over previous
//
#include <hip/hip_runtime.h>

constexpr int F_IN    = 4;
constexpr int R       = 1024;
constexpr int C       = 4096;
constexpr int N_CELLS = 8192;
constexpr int N_ENTRIES = 3 * N_CELLS;   // 24576

// Workspace layout (uint32 slots):
//   off[0..4096]     : CSR offsets (off[c]..off[c+1] = entries for column c)
//   cursor[0..4095]  : fill cursors
//   entries[0..24575]: packed (ia | ib<<12) — the other two indices of the cell
constexpr size_t WS_OFF     = 0;
constexpr size_t WS_CURSOR  = 4352;            // uint index (16-byte aligned)
constexpr size_t WS_ENTRIES = 4352 + 4096;     // uint index

// ---- build step 1: histogram counts into off[c+1] ----
__global__ void hist_kernel(const int* __restrict__ i0, const int* __restrict__ i1,
                            const int* __restrict__ i2, unsigned* __restrict__ off) {
    int n = blockIdx.x * blockDim.x + threadIdx.x;
    if (n < N_CELLS) {
        atomicAdd(&off[i0[n] + 1], 1u);
        atomicAdd(&off[i1[n] + 1], 1u);
        atomicAdd(&off[i2[n] + 1], 1u);
    }
}

// ---- build step 2: single-block prefix sum over 4096 counts ----
__global__ __launch_bounds__(1024) void scan_kernel(unsigned* __restrict__ off,
                                                    unsigned* __restrict__ cursor) {
    __shared__ unsigned part[1024];
    const int t = threadIdx.x;
    unsigned v0 = off[1 + 4 * t], v1 = off[2 + 4 * t],
             v2 = off[3 + 4 * t], v3 = off[4 + 4 * t];
    unsigned s0 = v0, s1 = s0 + v1, s2 = s1 + v2, s3 = s2 + v3;
    part[t] = s3;
    __syncthreads();
    for (int d = 1; d < 1024; d <<= 1) {
        unsigned x = (t >= d) ? part[t - d] : 0u;
        __syncthreads();
        part[t] += x;
        __syncthreads();
    }
    unsigned base = (t > 0) ? part[t - 1] : 0u;
    off[1 + 4 * t] = base + s0;
    off[2 + 4 * t] = base + s1;
    off[3 + 4 * t] = base + s2;
    off[4 + 4 * t] = base + s3;
    cursor[4 * t + 0] = base;
    cursor[4 * t + 1] = base + s0;
    cursor[4 * t + 2] = base + s1;
    cursor[4 * t + 3] = base + s2;
    if (t == 0) off[0] = 0u;
}

// ---- build step 3: fill CSR entries ----
__global__ void fill_kernel(const int* __restrict__ i0, const int* __restrict__ i1,
                            const int* __restrict__ i2, unsigned* __restrict__ cursor,
                            unsigned* __restrict__ entries) {
    int n = blockIdx.x * blockDim.x + threadIdx.x;
    if (n < N_CELLS) {
        unsigned a = (unsigned)i0[n], b = (unsigned)i1[n], c = (unsigned)i2[n];
        unsigned p;
        p = atomicAdd(&cursor[a], 1u); entries[p] = b | (c << 12);
        p = atomicAdd(&cursor[b], 1u); entries[p] = a | (c << 12);
        p = atomicAdd(&cursor[c], 1u); entries[p] = a | (b << 12);
    }
}

// ---- main: one block per (f, r); gather per owned column, no atomics ----
// part1[c] = sum over entries at c of row[ia]*row[ib]
// part0[c] = row[c] * part1[c]   (exact identity: every contribution at c is
//                                 mp3 = row[c] * pair_product)
__global__ __launch_bounds__(256) void gather_kernel(
    const float* __restrict__ in,
    const unsigned* __restrict__ off,
    const unsigned* __restrict__ entries,
    float* __restrict__ out)
{
    __shared__ float row[C];   // 16 KiB

    const int fr = blockIdx.x;
    const float* __restrict__ src = in + (size_t)fr * C;
    {
        const float4* src4 = reinterpret_cast<const float4*>(src);
        float4* row4 = reinterpret_cast<float4*>(row);
        for (int c = threadIdx.x; c < C / 4; c += blockDim.x)
            row4[c] = src4[c];
    }
    __syncthreads();

    float* __restrict__ out0 = out + (size_t)fr * C;                        // part0
    float* __restrict__ out1 = out + (size_t)F_IN * R * C + (size_t)fr * C; // part1

    for (int c = threadIdx.x; c < C; c += blockDim.x) {
        const unsigned e0 = off[c];
        const unsigned e1 = off[c + 1];
        float a1 = 0.f;
        for (unsigned e = e0; e < e1; ++e) {
            const unsigned p = entries[e];
            const float x = row[p & 4095u];
            const float y = row[(p >> 12) & 4095u];
            a1 = fmaf(x, y, a1);
        }
        const float own = row[c];
        out1[c] = a1;
        out0[c] = own * a1;
    }
}

extern "C" void kernel_launch(void* const* d_in, const int* in_sizes, int n_in,
                              void* d_out, int out_size, void* d_ws, size_t ws_size,
                              hipStream_t stream) {
    const float* in   = (const float*)d_in[0];
    const int*   idx0 = (const int*)d_in[1];
    const int*   idx1 = (const int*)d_in[2];
    const int*   idx2 = (const int*)d_in[3];
    float* out = (float*)d_out;

    unsigned* ws      = (unsigned*)d_ws;
    unsigned* off     = ws + WS_OFF;
    unsigned* cursor  = ws + WS_CURSOR;
    unsigned* entries = ws + WS_ENTRIES;

    // zero the histogram (off[0..4096])
    hipMemsetAsync(off, 0, (C + 1) * sizeof(unsigned), stream);

    dim3 b256(256);
    hist_kernel<<<dim3((N_CELLS + 255) / 256), b256, 0, stream>>>(idx0, idx1, idx2, off);
    scan_kernel<<<dim3(1), dim3(1024), 0, stream>>>(off, cursor);
    fill_kernel<<<dim3((N_CELLS + 255) / 256), b256, 0, stream>>>(idx0, idx1, idx2, cursor, entries);

    gather_kernel<<<dim3(F_IN * R), b256, 0, stream>>>(in, off, entries, out);
}

// Round 3
// 113.430 us; speedup vs baseline: 9.0374x; 1.1807x over previous
//
#include <hip/hip_runtime.h>

constexpr int F_IN    = 4;
constexpr int R       = 1024;
constexpr int C       = 4096;
constexpr int N_CELLS = 8192;

// Workspace layout (uint32 slots):
//   off[0..4096]     : CSR offsets (off[c]..off[c+1] = entries for column c)
//   cursor[0..4095]  : fill cursors
//   entries[0..24575]: packed (ia | ib<<12) — the other two indices of the cell
constexpr size_t WS_OFF     = 0;
constexpr size_t WS_CURSOR  = 4352;            // uint index (16-byte aligned)
constexpr size_t WS_ENTRIES = 4352 + 4096;     // uint index

// ---- build step 1: histogram counts into off[c+1] ----
__global__ void hist_kernel(const int* __restrict__ i0, const int* __restrict__ i1,
                            const int* __restrict__ i2, unsigned* __restrict__ off) {
    int n = blockIdx.x * blockDim.x + threadIdx.x;
    if (n < N_CELLS) {
        atomicAdd(&off[i0[n] + 1], 1u);
        atomicAdd(&off[i1[n] + 1], 1u);
        atomicAdd(&off[i2[n] + 1], 1u);
    }
}

// ---- build step 2: single-block prefix sum over 4096 counts ----
__global__ __launch_bounds__(1024) void scan_kernel(unsigned* __restrict__ off,
                                                    unsigned* __restrict__ cursor) {
    __shared__ unsigned part[1024];
    const int t = threadIdx.x;
    unsigned v0 = off[1 + 4 * t], v1 = off[2 + 4 * t],
             v2 = off[3 + 4 * t], v3 = off[4 + 4 * t];
    unsigned s0 = v0, s1 = s0 + v1, s2 = s1 + v2, s3 = s2 + v3;
    part[t] = s3;
    __syncthreads();
    for (int d = 1; d < 1024; d <<= 1) {
        unsigned x = (t >= d) ? part[t - d] : 0u;
        __syncthreads();
        part[t] += x;
        __syncthreads();
    }
    unsigned base = (t > 0) ? part[t - 1] : 0u;
    off[1 + 4 * t] = base + s0;
    off[2 + 4 * t] = base + s1;
    off[3 + 4 * t] = base + s2;
    off[4 + 4 * t] = base + s3;
    cursor[4 * t + 0] = base;
    cursor[4 * t + 1] = base + s0;
    cursor[4 * t + 2] = base + s1;
    cursor[4 * t + 3] = base + s2;
    if (t == 0) off[0] = 0u;
}

// ---- build step 3: fill CSR entries ----
__global__ void fill_kernel(const int* __restrict__ i0, const int* __restrict__ i1,
                            const int* __restrict__ i2, unsigned* __restrict__ cursor,
                            unsigned* __restrict__ entries) {
    int n = blockIdx.x * blockDim.x + threadIdx.x;
    if (n < N_CELLS) {
        unsigned a = (unsigned)i0[n], b = (unsigned)i1[n], c = (unsigned)i2[n];
        unsigned p;
        p = atomicAdd(&cursor[a], 1u); entries[p] = b | (c << 12);
        p = atomicAdd(&cursor[b], 1u); entries[p] = a | (c << 12);
        p = atomicAdd(&cursor[c], 1u); entries[p] = a | (b << 12);
    }
}

// ---- main: one block per r, all 4 f fused. LDS holds the 4 rows
// f-interleaved as float4 so each entry costs 2 ds_read_b128 + 4 FMA
// and the CSR walk is amortized over all 4 f-planes.
// part1[f][c] = sum entries row[f][ia]*row[f][ib]; part0 = row[f][c]*part1[f][c].
__global__ __launch_bounds__(1024) void gather_kernel(
    const float* __restrict__ in,
    const unsigned* __restrict__ off,
    const unsigned* __restrict__ entries,
    float* __restrict__ out)
{
    __shared__ float4 rows4[C];   // 64 KiB, rows4[c] = {f0,f1,f2,f3} at column c

    const int r = blockIdx.x;
    const int t = threadIdx.x;

    const float* __restrict__ p0 = in + ((size_t)0 * R + r) * C;
    const float* __restrict__ p1 = in + ((size_t)1 * R + r) * C;
    const float* __restrict__ p2 = in + ((size_t)2 * R + r) * C;
    const float* __restrict__ p3 = in + ((size_t)3 * R + r) * C;

    // Stage: lane-consecutive columns -> conflict-free ds_write_b128.
    #pragma unroll
    for (int j = 0; j < C / 1024; ++j) {
        const int c = t + j * 1024;
        rows4[c] = make_float4(p0[c], p1[c], p2[c], p3[c]);
    }
    __syncthreads();

    // Thread owns 4 consecutive columns c0..c0+3 (contiguous entry range).
    const unsigned c0 = (unsigned)t * 4u;
    const uint4 ov = *reinterpret_cast<const uint4*>(&off[c0]);
    const unsigned o4 = off[c0 + 4];

    float4 acc0 = make_float4(0.f, 0.f, 0.f, 0.f);
    float4 acc1 = acc0, acc2 = acc0, acc3 = acc0;

#define SUBLOOP(E0, E1, ACC)                                            \
    for (unsigned e = (E0); e < (E1); ++e) {                            \
        const unsigned p = entries[e];                                  \
        const float4 A = rows4[p & 4095u];                              \
        const float4 B = rows4[(p >> 12) & 4095u];                      \
        ACC.x = fmaf(A.x, B.x, ACC.x);                                  \
        ACC.y = fmaf(A.y, B.y, ACC.y);                                  \
        ACC.z = fmaf(A.z, B.z, ACC.z);                                  \
        ACC.w = fmaf(A.w, B.w, ACC.w);                                  \
    }
    SUBLOOP(ov.x, ov.y, acc0)
    SUBLOOP(ov.y, ov.z, acc1)
    SUBLOOP(ov.z, ov.w, acc2)
    SUBLOOP(ov.w, o4,   acc3)
#undef SUBLOOP

    // Own column values for the part0 = row * part1 identity.
    const float4 own0 = rows4[c0 + 0];
    const float4 own1 = rows4[c0 + 1];
    const float4 own2 = rows4[c0 + 2];
    const float4 own3 = rows4[c0 + 3];

#define STORES(F, COMP)                                                          \
    {                                                                            \
        float4 o1 = make_float4(acc0.COMP, acc1.COMP, acc2.COMP, acc3.COMP);     \
        float4 o0 = make_float4(own0.COMP * acc0.COMP, own1.COMP * acc1.COMP,    \
                                own2.COMP * acc2.COMP, own3.COMP * acc3.COMP);   \
        *reinterpret_cast<float4*>(out + ((size_t)(F) * R + r) * C + c0) = o0;   \
        *reinterpret_cast<float4*>(out + ((size_t)(F_IN + F) * R + r) * C + c0) = o1; \
    }
    STORES(0, x)
    STORES(1, y)
    STORES(2, z)
    STORES(3, w)
#undef STORES
}

extern "C" void kernel_launch(void* const* d_in, const int* in_sizes, int n_in,
                              void* d_out, int out_size, void* d_ws, size_t ws_size,
                              hipStream_t stream) {
    const float* in   = (const float*)d_in[0];
    const int*   idx0 = (const int*)d_in[1];
    const int*   idx1 = (const int*)d_in[2];
    const int*   idx2 = (const int*)d_in[3];
    float* out = (float*)d_out;

    unsigned* ws      = (unsigned*)d_ws;
    unsigned* off     = ws + WS_OFF;
    unsigned* cursor  = ws + WS_CURSOR;
    unsigned* entries = ws + WS_ENTRIES;

    hipMemsetAsync(off, 0, (C + 1) * sizeof(unsigned), stream);

    dim3 b256(256);
    hist_kernel<<<dim3((N_CELLS + 255) / 256), b256, 0, stream>>>(idx0, idx1, idx2, off);
    scan_kernel<<<dim3(1), dim3(1024), 0, stream>>>(off, cursor);
    fill_kernel<<<dim3((N_CELLS + 255) / 256), b256, 0, stream>>>(idx0, idx1, idx2, cursor, entries);

    gather_kernel<<<dim3(R), dim3(1024), 0, stream>>>(in, off, entries, out);
}